// Round 1
// baseline (264.280 us; speedup 1.0000x reference)
//
#include <hip/hip_runtime.h>

#define N_ROWS 32768
#define K_EMB  4096
#define D_DIM  64
#define NCHUNK 8
#define KC     (K_EMB / NCHUNK)   // 512

// ws layout (float offsets):
//   ee       : [0,       4096)
//   pval     : [4096,    266240)          8 * 32768
//   pidx(int): [266240,  528384)          8 * 32768
//   counts   : [528384,  532480)          4096
//   dw       : [532480,  794624)          4096*64
//   lossacc  : [794624,  794625)
//   n_scalar : [794625,  794626)
#define WS_EE     0
#define WS_PVAL   4096
#define WS_PIDX   266240
#define WS_COUNTS 528384
#define WS_DW     532480
#define WS_LOSS   794624
#define WS_N      794625

// out layout (float offsets):
#define O_ZQ    0
#define O_IDX   2097152
#define O_LOSS  2129920
#define O_EMB   2129921
#define O_CS    2392065
#define O_EMAW  2396161

__global__ void k_ee(const float* __restrict__ emb, float* __restrict__ ee) {
    int k = blockIdx.x * 256 + threadIdx.x;
    const float4* e4 = (const float4*)(emb + (size_t)k * D_DIM);
    float s0 = 0.f, s1 = 0.f, s2 = 0.f, s3 = 0.f;
#pragma unroll
    for (int i = 0; i < 16; ++i) {
        float4 v = e4[i];
        s0 = fmaf(v.x, v.x, s0);
        s1 = fmaf(v.y, v.y, s1);
        s2 = fmaf(v.z, v.z, s2);
        s3 = fmaf(v.w, v.w, s3);
    }
    ee[k] = (s0 + s1) + (s2 + s3);
}

__global__ __launch_bounds__(256) void k_argmin(
    const float* __restrict__ z, const float* __restrict__ emb,
    const float* __restrict__ ee, float* __restrict__ pval, int* __restrict__ pidx)
{
    const int n  = blockIdx.x * 256 + threadIdx.x;   // row
    const int c  = blockIdx.y;                        // K chunk
    const int k0 = c * KC;

    float4 zr[16];
    const float4* zp = (const float4*)(z + (size_t)n * D_DIM);
#pragma unroll
    for (int i = 0; i < 16; ++i) zr[i] = zp[i];

    // zz: only the exponent scale matters for the argmin quantization; any
    // reasonable fp32 accumulation order is fine.
    float s0 = 0.f, s1 = 0.f, s2 = 0.f, s3 = 0.f;
#pragma unroll
    for (int i = 0; i < 16; ++i) {
        s0 = fmaf(zr[i].x, zr[i].x, s0);
        s1 = fmaf(zr[i].y, zr[i].y, s1);
        s2 = fmaf(zr[i].z, zr[i].z, s2);
        s3 = fmaf(zr[i].w, zr[i].w, s3);
    }
    const float zz = (s0 + s1) + (s2 + s3);

    const float4* ep  = (const float4*)(emb + (size_t)k0 * D_DIM);
    const float*  eep = ee + k0;

    float best = 3.4e38f;
    int   bi   = k0;
#pragma unroll 2
    for (int kk = 0; kk < KC; ++kk) {
        float d0 = 0.f, d1 = 0.f, d2 = 0.f, d3 = 0.f;
#pragma unroll
        for (int i = 0; i < 16; ++i) {
            float4 ev = ep[kk * 16 + i];   // wave-uniform address: s_load or L1 broadcast
            d0 = fmaf(zr[i].x, ev.x, d0);
            d1 = fmaf(zr[i].y, ev.y, d1);
            d2 = fmaf(zr[i].z, ev.z, d2);
            d3 = fmaf(zr[i].w, ev.w, d3);
        }
        float dot = (d0 + d1) + (d2 + d3);
        // exact reference formula: fl(fl(zz+ee) - 2*dot); 2*dot is exact, so
        // FMA contraction here is bit-identical.
        float dv = (zz + eep[kk]) - 2.0f * dot;
        if (dv < best) { best = dv; bi = k0 + kk; }   // strict <: first-index tie-break
    }
    pval[(size_t)c * N_ROWS + n] = best;
    pidx[(size_t)c * N_ROWS + n] = bi;
}

__global__ void k_combine(const float* __restrict__ pval, int* __restrict__ pidx,
                          float* __restrict__ oidx)
{
    int n = blockIdx.x * 256 + threadIdx.x;
    float best = pval[n];
    int   bi   = pidx[n];
#pragma unroll
    for (int c = 1; c < NCHUNK; ++c) {
        float v = pval[(size_t)c * N_ROWS + n];
        int   i2 = pidx[(size_t)c * N_ROWS + n];
        if (v < best) { best = v; bi = i2; }  // ascending chunks: ties keep lower k
    }
    oidx[n]  = (float)bi;   // final index as float into d_out
    pidx[n]  = bi;          // reuse chunk-0 slot as the int index buffer
}

__global__ void k_scatter(const float* __restrict__ z, const float* __restrict__ emb,
                          const int* __restrict__ idxbuf, float* __restrict__ out_zq,
                          float* __restrict__ counts, float* __restrict__ dw,
                          float* __restrict__ lossacc)
{
    int t = blockIdx.x * 256 + threadIdx.x;
    float acc = 0.f;
#pragma unroll
    for (int i = 0; i < 16; ++i) {
        int e = t + i * 131072;            // 512*256 grid stride
        int nrow = e >> 6, d = e & 63;
        int k = idxbuf[nrow];
        float zv  = z[e];
        float evv = emb[(size_t)k * D_DIM + d];
        out_zq[e] = zv + (evv - zv);       // straight-through, bit-exact vs ref
        float diff = zv - evv;
        acc = fmaf(diff, diff, acc);
        atomicAdd(&dw[(size_t)k * D_DIM + d], zv);
        if (d == 0) atomicAdd(&counts[k], 1.0f);
    }
    __shared__ float red[256];
    red[threadIdx.x] = acc;
    __syncthreads();
    for (int s = 128; s > 0; s >>= 1) {
        if (threadIdx.x < s) red[threadIdx.x] += red[threadIdx.x + s];
        __syncthreads();
    }
    if (threadIdx.x == 0) atomicAdd(lossacc, red[0]);
}

__global__ void k_stats(const float* __restrict__ ema_cs, const float* __restrict__ counts,
                        const float* __restrict__ lossacc, float* __restrict__ out_cs,
                        float* __restrict__ out_loss, float* __restrict__ ws_n)
{
    __shared__ float red[256];
    float local = 0.f;
    for (int k = threadIdx.x; k < K_EMB; k += 256) {
        float v = 0.99f * ema_cs[k] + 0.01f * counts[k];
        out_cs[k] = v;
        local += v;
    }
    red[threadIdx.x] = local;
    __syncthreads();
    for (int s = 128; s > 0; s >>= 1) {
        if (threadIdx.x < s) red[threadIdx.x] += red[threadIdx.x + s];
        __syncthreads();
    }
    if (threadIdx.x == 0) {
        ws_n[0] = red[0];
        float m = lossacc[0] / 2097152.0f;
        out_loss[0] = 0.25f * m;
    }
}

__global__ void k_emb(const float* __restrict__ ema_w, const float* __restrict__ dw,
                      const float* __restrict__ out_cs, const float* __restrict__ ws_n,
                      float* __restrict__ out_emb, float* __restrict__ out_emaw)
{
    int e = blockIdx.x * 256 + threadIdx.x;
    int k = e >> 6;
    float nv = ws_n[0];
    float w  = 0.99f * ema_w[e] + 0.01f * dw[e];
    out_emaw[e] = w;
    float cs = (out_cs[k] + 1e-5f) / (nv + 0.04096f) * nv;
    out_emb[e] = w / cs;
}

extern "C" void kernel_launch(void* const* d_in, const int* in_sizes, int n_in,
                              void* d_out, int out_size, void* d_ws, size_t ws_size,
                              hipStream_t stream)
{
    const float* z      = (const float*)d_in[0];
    const float* emb    = (const float*)d_in[1];
    const float* ema_cs = (const float*)d_in[2];
    const float* ema_w  = (const float*)d_in[3];

    float* out   = (float*)d_out;
    float* o_zq  = out + O_ZQ;
    float* o_idx = out + O_IDX;
    float* o_ls  = out + O_LOSS;
    float* o_em  = out + O_EMB;
    float* o_cs  = out + O_CS;
    float* o_ew  = out + O_EMAW;

    float* w      = (float*)d_ws;
    float* ee     = w + WS_EE;
    float* pval   = w + WS_PVAL;
    int*   pidx   = (int*)(w + WS_PIDX);
    float* counts = w + WS_COUNTS;
    float* dw     = w + WS_DW;
    float* lossa  = w + WS_LOSS;
    float* ws_n   = w + WS_N;

    // zero counts+dw+loss+n in one contiguous memset
    hipMemsetAsync((char*)d_ws + (size_t)WS_COUNTS * 4, 0,
                   (size_t)(WS_N + 1 - WS_COUNTS) * 4, stream);

    k_ee<<<K_EMB / 256, 256, 0, stream>>>(emb, ee);
    k_argmin<<<dim3(N_ROWS / 256, NCHUNK), 256, 0, stream>>>(z, emb, ee, pval, pidx);
    k_combine<<<N_ROWS / 256, 256, 0, stream>>>(pval, pidx, o_idx);
    k_scatter<<<512, 256, 0, stream>>>(z, emb, pidx, o_zq, counts, dw, lossa);
    k_stats<<<1, 256, 0, stream>>>(ema_cs, counts, lossa, o_cs, o_ls, ws_n);
    k_emb<<<(K_EMB * D_DIM) / 256, 256, 0, stream>>>(ema_w, dw, o_cs, ws_n, o_em, o_ew);
}